// Round 2
// baseline (570.248 us; speedup 1.0000x reference)
//
#include <hip/hip_runtime.h>

#define NB    4096
#define TSTEP 256
#define BT    2          // batch elements per wave
#define DTC   0.01f

// tanh(a) = (E-1)/(E+1), E = exp(2a) via v_exp_f32 (exp2) + v_rcp_f32.
// Only the upper clamp is needed: exp2(very negative) -> 0 -> tanh -> -1 cleanly.
__device__ __forceinline__ float fast_tanh(float a) {
    float t = fminf(a * 2.885390082f, 126.0f);   // 2*log2(e)*a
    float E = __builtin_amdgcn_exp2f(t);
    return (E - 1.0f) * __builtin_amdgcn_rcpf(E + 1.0f);
}

// exp(a) for |a| small (<=~0.5 here): no clamp needed
__device__ __forceinline__ float fast_exp(float a) {
    return __builtin_amdgcn_exp2f(a * 1.44269504f);
}

__global__ __launch_bounds__(64, 2)
void koopman_kernel(const float* __restrict__ x,
                    const float* __restrict__ Wc1, const float* __restrict__ bc1,
                    const float* __restrict__ Wc2, const float* __restrict__ bc2,
                    const float* __restrict__ Wr1, const float* __restrict__ br1,
                    const float* __restrict__ Wr2, const float* __restrict__ br2,
                    float* __restrict__ out)
{
    const int lane = threadIdx.x;            // 0..63 = output feature
    const int blk  = blockIdx.x;             // 0..NB/BT-1

    __shared__ __align__(16) float lds_y[BT][64];
    __shared__ __align__(16) float lds_u[BT][96];   // [64..95] stays zero (r-lane pad reads)

    // ---- persistent weights in VGPRs for the whole sequence ----
    float w1[64], w2[48], b1, b2;
    if (lane < 48) {
        #pragma unroll
        for (int k = 0; k < 16; ++k)
            *reinterpret_cast<float4*>(&w1[k*4]) =
                *reinterpret_cast<const float4*>(&Wc1[lane*64 + k*4]);
        #pragma unroll
        for (int k = 0; k < 12; ++k)
            *reinterpret_cast<float4*>(&w2[k*4]) =
                *reinterpret_cast<const float4*>(&Wc2[lane*48 + k*4]);
        b1 = bc1[lane];
        b2 = bc2[lane];
    } else {
        const int r = lane - 48;
        #pragma unroll
        for (int k = 0; k < 16; ++k)
            *reinterpret_cast<float4*>(&w1[k*4]) =
                *reinterpret_cast<const float4*>(&Wr1[r*64 + k*4]);
        #pragma unroll
        for (int k = 0; k < 4; ++k)
            *reinterpret_cast<float4*>(&w2[k*4]) =
                *reinterpret_cast<const float4*>(&Wr2[r*16 + k*4]);
        #pragma unroll
        for (int k = 16; k < 48; ++k) w2[k] = 0.0f;
        b1 = br1[r];
        b2 = br2[r];
    }
    const int  ubase = (lane < 48) ? 0 : 48;  // layer-2 input window
    const float sgn  = (lane & 1) ? 1.0f : -1.0f;
    const bool  is_c = (lane < 48);
    const bool  odd  = (lane & 1) != 0;

    // ---- init state + per-element output pointers (bumped, no re-index) ----
    float  ysel[BT];
    float* po[BT];
    #pragma unroll
    for (int e = 0; e < BT; ++e) {
        const int el = blk * BT + e;
        ysel[e] = x[el * 64 + lane];
        lds_y[e][lane] = ysel[e];
        po[e] = out + (size_t)el * (TSTEP * 64) + lane;
    }
    if (lane < 32) {
        #pragma unroll
        for (int e = 0; e < BT; ++e) lds_u[e][64 + lane] = 0.0f;
    }
    __syncthreads();

    for (int t = 0; t < TSTEP; ++t) {
        // ---- layer 1: u = tanh(W1 @ y + b1); 4 partial accumulators x BT elems ----
        float a1[BT][4];
        #pragma unroll
        for (int e = 0; e < BT; ++e) {
            a1[e][0] = b1; a1[e][1] = 0.0f; a1[e][2] = 0.0f; a1[e][3] = 0.0f;
        }
        #pragma unroll
        for (int k4 = 0; k4 < 16; ++k4) {
            #pragma unroll
            for (int e = 0; e < BT; ++e) {
                const float4 yv = *reinterpret_cast<const float4*>(&lds_y[e][k4*4]);
                float acc = a1[e][k4 & 3];
                acc = fmaf(w1[k4*4+0], yv.x, acc);
                acc = fmaf(w1[k4*4+1], yv.y, acc);
                acc = fmaf(w1[k4*4+2], yv.z, acc);
                acc = fmaf(w1[k4*4+3], yv.w, acc);
                a1[e][k4 & 3] = acc;
            }
        }
        #pragma unroll
        for (int e = 0; e < BT; ++e) {
            const float s1 = (a1[e][0] + a1[e][1]) + (a1[e][2] + a1[e][3]);
            lds_u[e][lane] = fast_tanh(s1);
        }
        __syncthreads();

        // ---- layer 2: co/re = W2 @ u + b2 (block-diag, r-lanes zero-padded) ----
        float a2[BT][4];
        #pragma unroll
        for (int e = 0; e < BT; ++e) {
            a2[e][0] = b2; a2[e][1] = 0.0f; a2[e][2] = 0.0f; a2[e][3] = 0.0f;
        }
        #pragma unroll
        for (int k4 = 0; k4 < 12; ++k4) {
            #pragma unroll
            for (int e = 0; e < BT; ++e) {
                const float4 uv = *reinterpret_cast<const float4*>(&lds_u[e][ubase + k4*4]);
                float acc = a2[e][k4 & 3];
                acc = fmaf(w2[k4*4+0], uv.x, acc);
                acc = fmaf(w2[k4*4+1], uv.y, acc);
                acc = fmaf(w2[k4*4+2], uv.z, acc);
                acc = fmaf(w2[k4*4+3], uv.w, acc);
                a2[e][k4 & 3] = acc;
            }
        }

        // ---- pointwise update ----
        #pragma unroll
        for (int e = 0; e < BT; ++e) {
            const float co    = (a2[e][0] + a2[e][1]) + (a2[e][2] + a2[e][3]);
            const float other = __shfl_xor(co, 1, 64);
            const float mu = odd ? other : co;     // even slot of pair
            const float om = odd ? co    : other;  // odd slot of pair
            const float scale = fast_exp(DTC * mu);
            const float sv = __sinf(DTC * om) * scale;
            const float cv = __cosf(DTC * om) * scale;
            const float yo = __shfl_xor(ysel[e], 1, 64);
            // even lane: c*y_self - s*y_partner ; odd lane: c*y_self + s*y_partner
            const float ycnew = fmaf(cv, ysel[e], sgn * sv * yo);
            const float yrnew = fast_exp(DTC * co) * ysel[e];
            const float ynew  = is_c ? ycnew : yrnew;
            ysel[e] = ynew;
            lds_y[e][lane] = ynew;
            *po[e] = ynew;
            po[e] += 64;
        }
        __syncthreads();   // y visible for next step's layer-1 broadcast
    }
}

extern "C" void kernel_launch(void* const* d_in, const int* in_sizes, int n_in,
                              void* d_out, int out_size, void* d_ws, size_t ws_size,
                              hipStream_t stream) {
    const float* x   = (const float*)d_in[0];
    const float* Wc1 = (const float*)d_in[1];
    const float* bc1 = (const float*)d_in[2];
    const float* Wc2 = (const float*)d_in[3];
    const float* bc2 = (const float*)d_in[4];
    const float* Wr1 = (const float*)d_in[5];
    const float* br1 = (const float*)d_in[6];
    const float* Wr2 = (const float*)d_in[7];
    const float* br2 = (const float*)d_in[8];
    float* out = (float*)d_out;

    koopman_kernel<<<dim3(NB / BT), dim3(64), 0, stream>>>(
        x, Wc1, bc1, Wc2, bc2, Wr1, br1, Wr2, br2, out);
}

// Round 3
// 398.160 us; speedup vs baseline: 1.4322x; 1.4322x over previous
//
#include <hip/hip_runtime.h>

#define NB    4096
#define TSTEP 256
#define BT    2          // batch elements per wave
#define DTC   0.01f

// tanh(a) = (E-1)/(E+1), E = exp(2a) via v_exp_f32 (exp2) + v_rcp_f32.
// Upper clamp only: exp2(very negative) -> 0 -> tanh -> -1 cleanly.
__device__ __forceinline__ float fast_tanh(float a) {
    float t = fminf(a * 2.885390082f, 126.0f);   // 2*log2(e)*a
    float E = __builtin_amdgcn_exp2f(t);
    return (E - 1.0f) * __builtin_amdgcn_rcpf(E + 1.0f);
}

// exp(a) for small |a| (args here are dt-scaled, |a| << 1): no clamp needed
__device__ __forceinline__ float fast_exp(float a) {
    return __builtin_amdgcn_exp2f(a * 1.44269504f);
}

__global__ void __launch_bounds__(64) __attribute__((amdgpu_waves_per_eu(2, 2)))
koopman_kernel(const float* __restrict__ x,
               const float* __restrict__ Wc1, const float* __restrict__ bc1,
               const float* __restrict__ Wc2, const float* __restrict__ bc2,
               const float* __restrict__ Wr1, const float* __restrict__ br1,
               const float* __restrict__ Wr2, const float* __restrict__ br2,
               float* __restrict__ out)
{
    const int lane = threadIdx.x;            // 0..63 = output feature
    const int blk  = blockIdx.x;             // 0..NB/BT-1

    __shared__ __align__(16) float lds_y[BT][64];
    __shared__ __align__(16) float lds_u[BT][64];

    const bool is_c = (lane < 48);

    // ---- persistent weights: SROA-friendly (uniform pointer select, scalar loads,
    //      no address-taking on the private arrays) ----
    float w1[64], w2[48], b1, b2;
    {
        const float* p1 = is_c ? (Wc1 + lane * 64) : (Wr1 + (lane - 48) * 64);
        #pragma unroll
        for (int k = 0; k < 64; ++k) w1[k] = p1[k];

        const float* p2 = is_c ? (Wc2 + lane * 48) : (Wr2 + (lane - 48) * 16);
        #pragma unroll
        for (int k = 0; k < 48; ++k) {
            const bool valid = is_c || (k >= 32);
            const int  kk    = is_c ? k : (k >= 32 ? (k - 32) : 0);
            const float v    = p2[kk];
            w2[k] = valid ? v : 0.0f;
        }
        b1 = is_c ? bc1[lane] : br1[lane - 48];
        b2 = is_c ? bc2[lane] : br2[lane - 48];
    }
    // layer-2 input window: c-lanes read u[0..47]; r-lanes read u[16..63]
    // with w2[0..31] zeroed so only u[48..63] (their own tanh block) contributes.
    const int   ubase = is_c ? 0 : 16;
    const float sgn   = (lane & 1) ? 1.0f : -1.0f;
    const bool  odd   = (lane & 1) != 0;

    // ---- init state + bumped output pointers ----
    float  ysel[BT];
    float* po[BT];
    #pragma unroll
    for (int e = 0; e < BT; ++e) {
        const int el = blk * BT + e;
        ysel[e] = x[el * 64 + lane];
        lds_y[e][lane] = ysel[e];
        po[e] = out + (size_t)el * (TSTEP * 64) + lane;
    }
    __syncthreads();

    for (int t = 0; t < TSTEP; ++t) {
        // ---- layer 1: u = tanh(W1 @ y + b1); 4 partial accumulators x BT ----
        float a1[BT][4];
        #pragma unroll
        for (int e = 0; e < BT; ++e) {
            a1[e][0] = b1; a1[e][1] = 0.0f; a1[e][2] = 0.0f; a1[e][3] = 0.0f;
        }
        #pragma unroll
        for (int k4 = 0; k4 < 16; ++k4) {
            #pragma unroll
            for (int e = 0; e < BT; ++e) {
                const float4 yv = *reinterpret_cast<const float4*>(&lds_y[e][k4 * 4]);
                float acc = a1[e][k4 & 3];
                acc = fmaf(w1[k4*4+0], yv.x, acc);
                acc = fmaf(w1[k4*4+1], yv.y, acc);
                acc = fmaf(w1[k4*4+2], yv.z, acc);
                acc = fmaf(w1[k4*4+3], yv.w, acc);
                a1[e][k4 & 3] = acc;
            }
        }
        #pragma unroll
        for (int e = 0; e < BT; ++e) {
            const float s1 = (a1[e][0] + a1[e][1]) + (a1[e][2] + a1[e][3]);
            lds_u[e][lane] = fast_tanh(s1);
        }
        __syncthreads();

        // ---- layer 2: co/re = W2 @ u + b2 ----
        float a2[BT][4];
        #pragma unroll
        for (int e = 0; e < BT; ++e) {
            a2[e][0] = b2; a2[e][1] = 0.0f; a2[e][2] = 0.0f; a2[e][3] = 0.0f;
        }
        #pragma unroll
        for (int k4 = 0; k4 < 12; ++k4) {
            #pragma unroll
            for (int e = 0; e < BT; ++e) {
                const float4 uv = *reinterpret_cast<const float4*>(&lds_u[e][ubase + k4 * 4]);
                float acc = a2[e][k4 & 3];
                acc = fmaf(w2[k4*4+0], uv.x, acc);
                acc = fmaf(w2[k4*4+1], uv.y, acc);
                acc = fmaf(w2[k4*4+2], uv.z, acc);
                acc = fmaf(w2[k4*4+3], uv.w, acc);
                a2[e][k4 & 3] = acc;
            }
        }

        // ---- pointwise update ----
        #pragma unroll
        for (int e = 0; e < BT; ++e) {
            const float co    = (a2[e][0] + a2[e][1]) + (a2[e][2] + a2[e][3]);
            const float other = __shfl_xor(co, 1, 64);
            const float mu = odd ? other : co;     // even slot of pair
            const float om = odd ? co    : other;  // odd slot of pair
            const float scale = fast_exp(DTC * mu);
            const float sv = __sinf(DTC * om) * scale;
            const float cv = __cosf(DTC * om) * scale;
            const float yo = __shfl_xor(ysel[e], 1, 64);
            // even lane: c*y_self - s*y_partner ; odd lane: c*y_self + s*y_partner
            const float ycnew = fmaf(cv, ysel[e], sgn * sv * yo);
            const float yrnew = fast_exp(DTC * co) * ysel[e];
            const float ynew  = is_c ? ycnew : yrnew;
            ysel[e] = ynew;
            lds_y[e][lane] = ynew;
            *po[e] = ynew;
            po[e] += 64;
        }
        __syncthreads();   // y visible for next step's layer-1 broadcast
    }
}

extern "C" void kernel_launch(void* const* d_in, const int* in_sizes, int n_in,
                              void* d_out, int out_size, void* d_ws, size_t ws_size,
                              hipStream_t stream) {
    const float* x   = (const float*)d_in[0];
    const float* Wc1 = (const float*)d_in[1];
    const float* bc1 = (const float*)d_in[2];
    const float* Wc2 = (const float*)d_in[3];
    const float* bc2 = (const float*)d_in[4];
    const float* Wr1 = (const float*)d_in[5];
    const float* br1 = (const float*)d_in[6];
    const float* Wr2 = (const float*)d_in[7];
    const float* br2 = (const float*)d_in[8];
    float* out = (float*)d_out;

    koopman_kernel<<<dim3(NB / BT), dim3(64), 0, stream>>>(
        x, Wc1, bc1, Wc2, bc2, Wr1, br1, Wr2, br2, out);
}

// Round 4
// 295.866 us; speedup vs baseline: 1.9274x; 1.3457x over previous
//
#include <hip/hip_runtime.h>

#define NB    4096
#define TSTEP 256
#define BT    2          // batch elements per wave
#define DTC   0.01f

typedef float v2f __attribute__((ext_vector_type(2)));

// tanh(a) = (E-1)/(E+1), E = exp(2a) via v_exp_f32 + v_rcp_f32 (upper clamp only)
__device__ __forceinline__ float fast_tanh(float a) {
    float t = fminf(a * 2.885390082f, 126.0f);   // 2*log2(e)*a
    float E = __builtin_amdgcn_exp2f(t);
    return (E - 1.0f) * __builtin_amdgcn_rcpf(E + 1.0f);
}
// exp(a), |a| small here
__device__ __forceinline__ float fast_exp(float a) {
    return __builtin_amdgcn_exp2f(a * 1.44269504f);
}

__global__ void __launch_bounds__(64) __attribute__((amdgpu_waves_per_eu(2, 2)))
koopman_kernel(const float* __restrict__ x,
               const float* __restrict__ Wc1, const float* __restrict__ bc1,
               const float* __restrict__ Wc2, const float* __restrict__ bc2,
               const float* __restrict__ Wr1, const float* __restrict__ br1,
               const float* __restrict__ Wr2, const float* __restrict__ br2,
               float* __restrict__ out)
{
    const int lane = threadIdx.x;            // 0..63 = output feature
    const int blk  = blockIdx.x;             // 0..NB/BT-1

    __shared__ __align__(16) float lds_y[BT][64];
    __shared__ __align__(16) float lds_u[BT][64];

    const bool is_c = (lane < 48);

    // ---- persistent weights as float2 pairs (v_pk_fma_f32 operands) ----
    v2f w1[32], w2[24];
    float b1, b2;
    {
        const float* p1 = is_c ? (Wc1 + lane * 64) : (Wr1 + (lane - 48) * 64);
        #pragma unroll
        for (int k = 0; k < 32; ++k) {
            v2f tv; tv.x = p1[2*k]; tv.y = p1[2*k + 1]; w1[k] = tv;
        }
        const float* p2 = is_c ? (Wc2 + lane * 48) : (Wr2 + (lane - 48) * 16);
        #pragma unroll
        for (int k = 0; k < 24; ++k) {
            const bool valid = is_c || (k >= 16);          // r-lanes: only last 8 pairs real
            const int  kk    = is_c ? 2*k : (k >= 16 ? 2*k - 32 : 0);
            v2f tv; tv.x = valid ? p2[kk] : 0.0f; tv.y = valid ? p2[kk + 1] : 0.0f;
            w2[k] = tv;
        }
        b1 = is_c ? bc1[lane] : br1[lane - 48];
        b2 = is_c ? bc2[lane] : br2[lane - 48];
    }
    // layer-2 input window: c-lanes read u[0..47]; r-lanes read u[16..63] with
    // w2[0..15]=0 so only u[48..63] (their own tanh block) contributes.
    const int   ubase = is_c ? 0 : 16;
    const float sgn   = (lane & 1) ? 1.0f : -1.0f;
    const bool  odd   = (lane & 1) != 0;

    // ---- init state + 32-bit output offsets (out < 4G elements) ----
    float    ysel[BT];
    unsigned po[BT];
    #pragma unroll
    for (int e = 0; e < BT; ++e) {
        const int el = blk * BT + e;
        ysel[e] = x[el * 64 + lane];
        lds_y[e][lane] = ysel[e];
        po[e] = (unsigned)el * (TSTEP * 64) + lane;
    }
    __builtin_amdgcn_wave_barrier();   // single-wave WG: LDS pipe is in-order per wave

    for (int t = 0; t < TSTEP; ++t) {
        // ---- layer 1: u = tanh(W1 @ y + b1). Batch all 16 ds_read_b128 first
        //      (forces wide live range -> ILP), then packed-fp32 FMAs. ----
        #pragma unroll
        for (int e = 0; e < BT; ++e) {
            float4 yq[16];
            #pragma unroll
            for (int k = 0; k < 16; ++k)
                yq[k] = *reinterpret_cast<const float4*>(&lds_y[e][k * 4]);
            v2f accA, accB, accC, accD;
            accA.x = b1; accA.y = 0.0f;
            accB.x = 0.0f; accB.y = 0.0f;
            accC = accB; accD = accB;
            #pragma unroll
            for (int k = 0; k < 16; ++k) {
                v2f lo; lo.x = yq[k].x; lo.y = yq[k].y;
                v2f hi; hi.x = yq[k].z; hi.y = yq[k].w;
                if (k & 1) {
                    accC = __builtin_elementwise_fma(w1[2*k],     lo, accC);
                    accD = __builtin_elementwise_fma(w1[2*k + 1], hi, accD);
                } else {
                    accA = __builtin_elementwise_fma(w1[2*k],     lo, accA);
                    accB = __builtin_elementwise_fma(w1[2*k + 1], hi, accB);
                }
            }
            const v2f sv2 = (accA + accB) + (accC + accD);
            lds_u[e][lane] = fast_tanh(sv2.x + sv2.y);
        }
        __builtin_amdgcn_wave_barrier();

        // ---- layer 2: co/re = W2 @ u + b2 ----
        float co[BT];
        #pragma unroll
        for (int e = 0; e < BT; ++e) {
            float4 uq[12];
            #pragma unroll
            for (int k = 0; k < 12; ++k)
                uq[k] = *reinterpret_cast<const float4*>(&lds_u[e][ubase + k * 4]);
            v2f accA, accB, accC, accD;
            accA.x = b2; accA.y = 0.0f;
            accB.x = 0.0f; accB.y = 0.0f;
            accC = accB; accD = accB;
            #pragma unroll
            for (int k = 0; k < 12; ++k) {
                v2f lo; lo.x = uq[k].x; lo.y = uq[k].y;
                v2f hi; hi.x = uq[k].z; hi.y = uq[k].w;
                if (k & 1) {
                    accC = __builtin_elementwise_fma(w2[2*k],     lo, accC);
                    accD = __builtin_elementwise_fma(w2[2*k + 1], hi, accD);
                } else {
                    accA = __builtin_elementwise_fma(w2[2*k],     lo, accA);
                    accB = __builtin_elementwise_fma(w2[2*k + 1], hi, accB);
                }
            }
            const v2f sv2 = (accA + accB) + (accC + accD);
            co[e] = sv2.x + sv2.y;
        }

        // ---- pointwise update ----
        #pragma unroll
        for (int e = 0; e < BT; ++e) {
            const float other = __shfl_xor(co[e], 1, 64);
            const float mu = odd ? other : co[e];   // even slot of pair
            const float om = odd ? co[e] : other;   // odd slot of pair
            const float scale = fast_exp(DTC * mu);
            const float omr = om * 1.59154943e-3f;  // dt*om / (2*pi) (v_sin takes revolutions)
            const float sv = __builtin_amdgcn_sinf(omr) * scale;
            const float cv = __builtin_amdgcn_cosf(omr) * scale;
            const float yo = __shfl_xor(ysel[e], 1, 64);
            // even lane: c*y_self - s*y_partner ; odd lane: c*y_self + s*y_partner
            const float ycnew = fmaf(cv, ysel[e], sgn * sv * yo);
            const float yrnew = fast_exp(DTC * co[e]) * ysel[e];
            const float ynew  = is_c ? ycnew : yrnew;
            ysel[e] = ynew;
            lds_y[e][lane] = ynew;
            out[po[e]] = ynew;
            po[e] += 64;
        }
        __builtin_amdgcn_wave_barrier();   // order lds_y writes before next-iter reads
    }
}

extern "C" void kernel_launch(void* const* d_in, const int* in_sizes, int n_in,
                              void* d_out, int out_size, void* d_ws, size_t ws_size,
                              hipStream_t stream) {
    const float* x   = (const float*)d_in[0];
    const float* Wc1 = (const float*)d_in[1];
    const float* bc1 = (const float*)d_in[2];
    const float* Wc2 = (const float*)d_in[3];
    const float* bc2 = (const float*)d_in[4];
    const float* Wr1 = (const float*)d_in[5];
    const float* br1 = (const float*)d_in[6];
    const float* Wr2 = (const float*)d_in[7];
    const float* br2 = (const float*)d_in[8];
    float* out = (float*)d_out;

    koopman_kernel<<<dim3(NB / BT), dim3(64), 0, stream>>>(
        x, Wc1, bc1, Wc2, bc2, Wr1, br1, Wr2, br2, out);
}